// Round 1
// baseline (6536.814 us; speedup 1.0000x reference)
//
#include <hip/hip_runtime.h>
#include <math.h>

#define C_DIM 64
#define N_B 2
#define SPATIAL (64*64*64)
#define PLANE_SZ (64*64)
#define EPSV 1e-5f

// ---------------- K1: per-channel sum & sumsq ----------------
// grid: 64 channels * 16 parts, 256 threads
__global__ __launch_bounds__(256) void k_stats(const float* __restrict__ x,
                                               float* __restrict__ wsf) {
    int c = blockIdx.x >> 4;
    int part = blockIdx.x & 15;
    int tid = threadIdx.x;
    const int per_part = SPATIAL / 16;  // 16384 floats
    float s = 0.f, sq = 0.f;
    for (int n = 0; n < N_B; ++n) {
        const float* base = x + ((size_t)(n * C_DIM + c)) * SPATIAL + (size_t)part * per_part;
        const float4* b4 = (const float4*)base;
        #pragma unroll
        for (int it = 0; it < 16; ++it) {
            float4 v = b4[it * 256 + tid];
            s  += v.x + v.y + v.z + v.w;
            sq += v.x*v.x + v.y*v.y + v.z*v.z + v.w*v.w;
        }
    }
    __shared__ float rs[256], rq[256];
    rs[tid] = s; rq[tid] = sq;
    __syncthreads();
    for (int off = 128; off > 0; off >>= 1) {
        if (tid < off) { rs[tid] += rs[tid+off]; rq[tid] += rq[tid+off]; }
        __syncthreads();
    }
    if (tid == 0) {
        atomicAdd(&wsf[c], rs[0]);
        atomicAdd(&wsf[64 + c], rq[0]);
    }
}

// ---------------- K1b: finalize scale/shift ----------------
__global__ void k_finalize(float* __restrict__ wsf,
                           const float* __restrict__ gamma,
                           const float* __restrict__ beta) {
    int c = threadIdx.x;
    float cnt = (float)(N_B * SPATIAL);
    float mean = wsf[c] / cnt;
    float var = wsf[64 + c] / cnt - mean * mean;
    float sc = gamma[c] * rsqrtf(var + EPSV);
    wsf[128 + c] = sc;
    wsf[192 + c] = beta[c] - mean * sc;
}

// ---------------- K2: fused normalize + depthwise 5x5x5 (pad 2) ----------------
// tile: 8(d, reg-blocked) x 8(h) x 32(w), 256 threads (32w x 8h)
#define K2D 12
#define K2H 12
#define K2W 36
__global__ __launch_bounds__(256) void k_conv5(const float* __restrict__ x,
                                               const float* __restrict__ w0,
                                               const float* __restrict__ b0,
                                               const float* __restrict__ wsf,
                                               float* __restrict__ attn0) {
    __shared__ float sh[K2D * K2H * K2W];
    __shared__ float wt[125];
    int tid = threadIdx.x;
    int tx = tid & 31;
    int ty = tid >> 5;
    int wtile = blockIdx.x;        // 0..1
    int dt = blockIdx.y & 7;       // 0..7
    int ht = blockIdx.y >> 3;      // 0..7
    int nc = blockIdx.z;           // 0..127
    int c = nc & 63;
    int w0i = wtile * 32;
    int h0 = ht * 8;
    int d0 = dt * 8;
    const float* xb = x + (size_t)nc * SPATIAL;
    float sc = wsf[128 + c], shv = wsf[192 + c];
    if (tid < 125) wt[tid] = w0[c * 125 + tid];
    for (int idx = tid; idx < K2D * K2H * K2W; idx += 256) {
        int z = idx / (K2H * K2W);
        int rem = idx - z * (K2H * K2W);
        int y = rem / K2W;
        int xw = rem - y * K2W;
        int gd = d0 - 2 + z, gh = h0 - 2 + y, gw = w0i - 2 + xw;
        float v = 0.f;
        if ((unsigned)gd < 64u && (unsigned)gh < 64u && (unsigned)gw < 64u)
            v = xb[(size_t)gd * PLANE_SZ + gh * 64 + gw] * sc + shv;
        sh[idx] = v;
    }
    __syncthreads();
    float acc[8] = {0,0,0,0,0,0,0,0};
    #pragma unroll
    for (int z = 0; z < 12; ++z) {
        #pragma unroll
        for (int j = 0; j < 5; ++j) {
            #pragma unroll
            for (int k = 0; k < 5; ++k) {
                float v = sh[(z * K2H + (ty + j)) * K2W + tx + k];
                #pragma unroll
                for (int i = 0; i < 5; ++i) {
                    int dz = z - i;
                    if (dz >= 0 && dz < 8)
                        acc[dz] += wt[(i * 5 + j) * 5 + k] * v;
                }
            }
        }
    }
    float bias = b0[c];
    float* ob = attn0 + (size_t)nc * SPATIAL + (size_t)(h0 + ty) * 64 + w0i + tx;
    #pragma unroll
    for (int dz = 0; dz < 8; ++dz)
        ob[(size_t)(d0 + dz) * PLANE_SZ] = acc[dz] + bias;
}

// ---------------- K3: dilated depthwise 7x7x7, dil=3, pad 9 ----------------
// thread = (h,w) column, 8 d-outputs register-blocked; taps loaded direct from global
__global__ __launch_bounds__(256) void k_conv7(const float* __restrict__ attn0,
                                               const float* __restrict__ wsv,
                                               const float* __restrict__ bs,
                                               float* __restrict__ attn1) {
    __shared__ float wt[343];
    int tid = threadIdx.x;
    int w = tid & 63;
    int hh = tid >> 6;             // 0..3
    int ht = blockIdx.x;           // 0..15
    int dt = blockIdx.y;           // 0..7
    int nc = blockIdx.z;
    int c = nc & 63;
    int h = ht * 4 + hh;
    int d0 = dt * 8;
    for (int i = tid; i < 343; i += 256) wt[i] = wsv[c * 343 + i];
    __syncthreads();
    const float* ab = attn0 + (size_t)nc * SPATIAL;
    float acc[8] = {0,0,0,0,0,0,0,0};
    #pragma unroll
    for (int p = 0; p < 26; ++p) {           // plane z = d0 - 9 + p; q = p - 3t
        int z = d0 - 9 + p;
        if (z < 0 || z >= 64) continue;
        const float* pb = ab + (size_t)z * PLANE_SZ;
        for (int v = 0; v < 7; ++v) {
            int y = h + 3 * v - 9;
            if (y < 0 || y >= 64) continue;
            const float* rb = pb + y * 64;
            for (int u = 0; u < 7; ++u) {
                int xw = w + 3 * u - 9;
                float val = ((unsigned)xw < 64u) ? rb[xw] : 0.f;
                #pragma unroll
                for (int t = 0; t < 7; ++t) {
                    int q = p - 3 * t;
                    if (q >= 0 && q < 8)
                        acc[q] += wt[t * 49 + v * 7 + u] * val;
                }
            }
        }
    }
    float bias = bs[c];
    float* ob = attn1 + (size_t)nc * SPATIAL + (size_t)h * 64 + w;
    #pragma unroll
    for (int q = 0; q < 8; ++q)
        ob[(size_t)(d0 + q) * PLANE_SZ] = acc[q] + bias;
}

// ---------------- K4: pointwise 1x1x1 (64->64) + bias + gate by x ----------------
// block: 64 spatial x 64 channels tile; wave-uniform channel group
__global__ __launch_bounds__(256) void k_pointwise(const float* __restrict__ attn1,
                                                   const float* __restrict__ x,
                                                   const float* __restrict__ w1,
                                                   const float* __restrict__ b1,
                                                   float* __restrict__ out) {
    __shared__ float at[64 * 64];
    int tid = threadIdx.x;
    int sl = tid & 63;
    int cg = __builtin_amdgcn_readfirstlane(tid >> 6);  // 0..3, wave-uniform
    int s0 = blockIdx.x * 64;
    int n = blockIdx.y;
    const float* a_base = attn1 + (size_t)n * C_DIM * SPATIAL + s0;
    #pragma unroll
    for (int it = 0; it < 16; ++it) {
        int idx = it * 256 + tid;
        int row = idx >> 6;
        at[idx] = a_base[(size_t)row * SPATIAL + sl];
    }
    __syncthreads();
    float acc[16];
    #pragma unroll
    for (int j = 0; j < 16; ++j) acc[j] = 0.f;
    for (int ci = 0; ci < 64; ++ci) {
        float va = at[ci * 64 + sl];
        #pragma unroll
        for (int j = 0; j < 16; ++j) {
            int cc = cg * 16 + j;
            acc[j] += w1[cc * 64 + ci] * va;   // wave-uniform -> scalar loads
        }
    }
    const float* xb = x + (size_t)n * C_DIM * SPATIAL + s0;
    float* ob = out + (size_t)n * C_DIM * SPATIAL + s0;
    #pragma unroll
    for (int j = 0; j < 16; ++j) {
        int cc = cg * 16 + j;
        float attn = acc[j] + b1[cc];
        ob[(size_t)cc * SPATIAL + sl] = xb[(size_t)cc * SPATIAL + sl] * attn;
    }
}

extern "C" void kernel_launch(void* const* d_in, const int* in_sizes, int n_in,
                              void* d_out, int out_size, void* d_ws, size_t ws_size,
                              hipStream_t stream) {
    const float* x     = (const float*)d_in[0];
    const float* gamma = (const float*)d_in[1];
    const float* beta  = (const float*)d_in[2];
    const float* w0    = (const float*)d_in[3];
    const float* b0    = (const float*)d_in[4];
    const float* wsv   = (const float*)d_in[5];
    const float* bs    = (const float*)d_in[6];
    const float* w1    = (const float*)d_in[7];
    const float* b1    = (const float*)d_in[8];
    float* out = (float*)d_out;
    float* wsf = (float*)d_ws;
    float* attn1 = wsf + 256;   // 134 MB intermediate in workspace

    hipMemsetAsync(d_ws, 0, 1024, stream);
    k_stats<<<dim3(1024), dim3(256), 0, stream>>>(x, wsf);
    k_finalize<<<dim3(1), dim3(64), 0, stream>>>(wsf, gamma, beta);
    // attn0 lives in d_out; overwritten later by K4 (stream-ordered, safe)
    k_conv5<<<dim3(2, 64, 128), dim3(256), 0, stream>>>(x, w0, b0, wsf, out);
    k_conv7<<<dim3(16, 8, 128), dim3(256), 0, stream>>>(out, wsv, bs, attn1);
    k_pointwise<<<dim3(4096, 2), dim3(256), 0, stream>>>(attn1, x, w1, b1, out);
}

// Round 2
// 3766.317 us; speedup vs baseline: 1.7356x; 1.7356x over previous
//
#include <hip/hip_runtime.h>
#include <math.h>

#define C_DIM 64
#define N_B 2
#define SPATIAL (64*64*64)
#define PLANE_SZ (64*64)
#define EPSV 1e-5f

// ---------------- K1: per-channel sum & sumsq ----------------
__global__ __launch_bounds__(256) void k_stats(const float* __restrict__ x,
                                               float* __restrict__ wsf) {
    int c = blockIdx.x >> 4;
    int part = blockIdx.x & 15;
    int tid = threadIdx.x;
    const int per_part = SPATIAL / 16;  // 16384 floats
    float s = 0.f, sq = 0.f;
    for (int n = 0; n < N_B; ++n) {
        const float* base = x + ((size_t)(n * C_DIM + c)) * SPATIAL + (size_t)part * per_part;
        const float4* b4 = (const float4*)base;
        #pragma unroll
        for (int it = 0; it < 16; ++it) {
            float4 v = b4[it * 256 + tid];
            s  += v.x + v.y + v.z + v.w;
            sq += v.x*v.x + v.y*v.y + v.z*v.z + v.w*v.w;
        }
    }
    __shared__ float rs[256], rq[256];
    rs[tid] = s; rq[tid] = sq;
    __syncthreads();
    for (int off = 128; off > 0; off >>= 1) {
        if (tid < off) { rs[tid] += rs[tid+off]; rq[tid] += rq[tid+off]; }
        __syncthreads();
    }
    if (tid == 0) {
        atomicAdd(&wsf[c], rs[0]);
        atomicAdd(&wsf[64 + c], rq[0]);
    }
}

// ---------------- K1b: finalize scale/shift ----------------
__global__ void k_finalize(float* __restrict__ wsf,
                           const float* __restrict__ gamma,
                           const float* __restrict__ beta) {
    int c = threadIdx.x;
    float cnt = (float)(N_B * SPATIAL);
    float mean = wsf[c] / cnt;
    float var = wsf[64 + c] / cnt - mean * mean;
    float sc = gamma[c] * rsqrtf(var + EPSV);
    wsf[128 + c] = sc;
    wsf[192 + c] = beta[c] - mean * sc;
}

// ---------------- K2: fused normalize + depthwise 5x5x5 (pad 2) ----------------
#define K2D 12
#define K2H 12
#define K2W 36
__global__ __launch_bounds__(256) void k_conv5(const float* __restrict__ x,
                                               const float* __restrict__ w0,
                                               const float* __restrict__ b0,
                                               const float* __restrict__ wsf,
                                               float* __restrict__ attn0) {
    __shared__ float sh[K2D * K2H * K2W];
    __shared__ float wt[125];
    int tid = threadIdx.x;
    int tx = tid & 31;
    int ty = tid >> 5;
    int wtile = blockIdx.x;        // 0..1
    int dt = blockIdx.y & 7;       // 0..7
    int ht = blockIdx.y >> 3;      // 0..7
    int nc = blockIdx.z;           // 0..127
    int c = nc & 63;
    int w0i = wtile * 32;
    int h0 = ht * 8;
    int d0 = dt * 8;
    const float* xb = x + (size_t)nc * SPATIAL;
    float sc = wsf[128 + c], shv = wsf[192 + c];
    if (tid < 125) wt[tid] = w0[c * 125 + tid];
    for (int idx = tid; idx < K2D * K2H * K2W; idx += 256) {
        int z = idx / (K2H * K2W);
        int rem = idx - z * (K2H * K2W);
        int y = rem / K2W;
        int xw = rem - y * K2W;
        int gd = d0 - 2 + z, gh = h0 - 2 + y, gw = w0i - 2 + xw;
        float v = 0.f;
        if ((unsigned)gd < 64u && (unsigned)gh < 64u && (unsigned)gw < 64u)
            v = xb[(size_t)gd * PLANE_SZ + gh * 64 + gw] * sc + shv;
        sh[idx] = v;
    }
    __syncthreads();
    float acc[8] = {0,0,0,0,0,0,0,0};
    #pragma unroll
    for (int z = 0; z < 12; ++z) {
        #pragma unroll
        for (int j = 0; j < 5; ++j) {
            #pragma unroll
            for (int k = 0; k < 5; ++k) {
                float v = sh[(z * K2H + (ty + j)) * K2W + tx + k];
                #pragma unroll
                for (int i = 0; i < 5; ++i) {
                    int dz = z - i;
                    if (dz >= 0 && dz < 8)
                        acc[dz] += wt[(i * 5 + j) * 5 + k] * v;
                }
            }
        }
    }
    float bias = b0[c];
    float* ob = attn0 + (size_t)nc * SPATIAL + (size_t)(h0 + ty) * 64 + w0i + tx;
    #pragma unroll
    for (int dz = 0; dz < 8; ++dz)
        ob[(size_t)(d0 + dz) * PLANE_SZ] = acc[dz] + bias;
}

// ---------------- K3 v2: dilated depthwise 7x7x7, dil=3, pad 9 ----------------
// Residue decomposition in d: thread computes 8 outputs d = 3*(j0+q)+rd (q=0..7).
// Input planes z = 3*m+rd, m = j0-3+p (p=0..13) form a DENSE sequence; the
// scatter is q = p - t, compile-time under full p-unroll (dense 7-tap conv).
// Each plane-slice (22 rows x 82 cols, zero-padded halo) staged in LDS ->
// compute has NO bound checks, ds_read with immediate offsets. Weights read
// with wave-uniform index -> scalar s_load (off the VALU pipe).
#define ROWS7 22
#define COLS7 84   /* 82 valid + 2 pad */
__global__ __launch_bounds__(256) void k_conv7(const float* __restrict__ attn0,
                                               const float* __restrict__ wsv,
                                               const float* __restrict__ bs,
                                               float* __restrict__ attn1) {
    __shared__ float sh[ROWS7 * COLS7];
    int tid = threadIdx.x;
    int w = tid & 63;
    int hh = tid >> 6;             // 0..3, wave-uniform
    int ht = blockIdx.x;           // 0..15
    int rd = blockIdx.y % 3;       // residue class in d
    int j0 = (blockIdx.y / 3) * 8; // 0,8,16
    int nc = blockIdx.z;
    int c = nc & 63;
    int h0 = ht * 4;
    int h = h0 + hh;
    const float* ab = attn0 + (size_t)nc * SPATIAL;
    const float* wc = wsv + c * 343;   // uniform -> s_load
    float acc[8] = {0,0,0,0,0,0,0,0};

    #pragma unroll
    for (int p = 0; p < 14; ++p) {
        int m = j0 - 3 + p;
        int z = 3 * m + rd;
        bool zok = (m >= 0) && (z < 64);   // block-uniform
        __syncthreads();
        if (zok) {
            const float* pb = ab + (size_t)z * PLANE_SZ;
            for (int idx = tid; idx < ROWS7 * COLS7; idx += 256) {
                int row = idx / COLS7;
                int col = idx - row * COLS7;
                int gy = h0 - 9 + row;
                int gx = col - 9;
                float v = 0.f;
                if (col < 82 && (unsigned)gy < 64u && (unsigned)gx < 64u)
                    v = pb[gy * 64 + gx];
                sh[idx] = v;
            }
        }
        __syncthreads();
        if (zok) {
            #pragma unroll
            for (int v = 0; v < 7; ++v) {
                float val[7];
                int rb = (hh + 3 * v) * COLS7 + w;
                #pragma unroll
                for (int u = 0; u < 7; ++u) val[u] = sh[rb + 3 * u];
                #pragma unroll
                for (int t = 0; t < 7; ++t) {
                    int q = p - t;
                    if (q >= 0 && q < 8) {
                        #pragma unroll
                        for (int u = 0; u < 7; ++u)
                            acc[q] = fmaf(wc[t * 49 + v * 7 + u], val[u], acc[q]);
                    }
                }
            }
        }
    }
    float bias = bs[c];
    float* ob = attn1 + (size_t)nc * SPATIAL + (size_t)h * 64 + w;
    #pragma unroll
    for (int q = 0; q < 8; ++q) {
        int d = 3 * (j0 + q) + rd;
        if (d < 64)
            ob[(size_t)d * PLANE_SZ] = acc[q] + bias;
    }
}

// ---------------- K4: pointwise 1x1x1 (64->64) + bias + gate by x ----------------
__global__ __launch_bounds__(256) void k_pointwise(const float* __restrict__ attn1,
                                                   const float* __restrict__ x,
                                                   const float* __restrict__ w1,
                                                   const float* __restrict__ b1,
                                                   float* __restrict__ out) {
    __shared__ float at[64 * 64];
    int tid = threadIdx.x;
    int sl = tid & 63;
    int cg = __builtin_amdgcn_readfirstlane(tid >> 6);  // 0..3, wave-uniform
    int s0 = blockIdx.x * 64;
    int n = blockIdx.y;
    const float* a_base = attn1 + (size_t)n * C_DIM * SPATIAL + s0;
    #pragma unroll
    for (int it = 0; it < 16; ++it) {
        int idx = it * 256 + tid;
        int row = idx >> 6;
        at[idx] = a_base[(size_t)row * SPATIAL + sl];
    }
    __syncthreads();
    float acc[16];
    #pragma unroll
    for (int j = 0; j < 16; ++j) acc[j] = 0.f;
    for (int ci = 0; ci < 64; ++ci) {
        float va = at[ci * 64 + sl];
        #pragma unroll
        for (int j = 0; j < 16; ++j) {
            int cc = cg * 16 + j;
            acc[j] += w1[cc * 64 + ci] * va;   // wave-uniform -> scalar loads
        }
    }
    const float* xb = x + (size_t)n * C_DIM * SPATIAL + s0;
    float* ob = out + (size_t)n * C_DIM * SPATIAL + s0;
    #pragma unroll
    for (int j = 0; j < 16; ++j) {
        int cc = cg * 16 + j;
        float attn = acc[j] + b1[cc];
        ob[(size_t)cc * SPATIAL + sl] = xb[(size_t)cc * SPATIAL + sl] * attn;
    }
}

extern "C" void kernel_launch(void* const* d_in, const int* in_sizes, int n_in,
                              void* d_out, int out_size, void* d_ws, size_t ws_size,
                              hipStream_t stream) {
    const float* x     = (const float*)d_in[0];
    const float* gamma = (const float*)d_in[1];
    const float* beta  = (const float*)d_in[2];
    const float* w0    = (const float*)d_in[3];
    const float* b0    = (const float*)d_in[4];
    const float* wsv   = (const float*)d_in[5];
    const float* bs    = (const float*)d_in[6];
    const float* w1    = (const float*)d_in[7];
    const float* b1    = (const float*)d_in[8];
    float* out = (float*)d_out;
    float* wsf = (float*)d_ws;
    float* attn1 = wsf + 256;   // 134 MB intermediate in workspace

    hipMemsetAsync(d_ws, 0, 1024, stream);
    k_stats<<<dim3(1024), dim3(256), 0, stream>>>(x, wsf);
    k_finalize<<<dim3(1), dim3(64), 0, stream>>>(wsf, gamma, beta);
    // attn0 lives in d_out; overwritten later by K4 (stream-ordered, safe)
    k_conv5<<<dim3(2, 64, 128), dim3(256), 0, stream>>>(x, w0, b0, wsf, out);
    k_conv7<<<dim3(16, 9, 128), dim3(256), 0, stream>>>(out, wsv, bs, attn1);
    k_pointwise<<<dim3(4096, 2), dim3(256), 0, stream>>>(attn1, x, w1, b1, out);
}

// Round 3
// 1319.619 us; speedup vs baseline: 4.9536x; 2.8541x over previous
//
#include <hip/hip_runtime.h>
#include <math.h>

#define C_DIM 64
#define N_B 2
#define SPATIAL (64*64*64)
#define PLANE_SZ (64*64)
#define EPSV 1e-5f

// ---------------- K1: per-channel sum & sumsq ----------------
__global__ __launch_bounds__(256) void k_stats(const float* __restrict__ x,
                                               float* __restrict__ wsf) {
    int c = blockIdx.x >> 4;
    int part = blockIdx.x & 15;
    int tid = threadIdx.x;
    const int per_part = SPATIAL / 16;  // 16384 floats
    float s = 0.f, sq = 0.f;
    for (int n = 0; n < N_B; ++n) {
        const float* base = x + ((size_t)(n * C_DIM + c)) * SPATIAL + (size_t)part * per_part;
        const float4* b4 = (const float4*)base;
        #pragma unroll
        for (int it = 0; it < 16; ++it) {
            float4 v = b4[it * 256 + tid];
            s  += v.x + v.y + v.z + v.w;
            sq += v.x*v.x + v.y*v.y + v.z*v.z + v.w*v.w;
        }
    }
    __shared__ float rs[256], rq[256];
    rs[tid] = s; rq[tid] = sq;
    __syncthreads();
    for (int off = 128; off > 0; off >>= 1) {
        if (tid < off) { rs[tid] += rs[tid+off]; rq[tid] += rq[tid+off]; }
        __syncthreads();
    }
    if (tid == 0) {
        atomicAdd(&wsf[c], rs[0]);
        atomicAdd(&wsf[64 + c], rq[0]);
    }
}

// ---------------- K1b: finalize scale/shift ----------------
__global__ void k_finalize(float* __restrict__ wsf,
                           const float* __restrict__ gamma,
                           const float* __restrict__ beta) {
    int c = threadIdx.x;
    float cnt = (float)(N_B * SPATIAL);
    float mean = wsf[c] / cnt;
    float var = wsf[64 + c] / cnt - mean * mean;
    float sc = gamma[c] * rsqrtf(var + EPSV);
    wsf[128 + c] = sc;
    wsf[192 + c] = beta[c] - mean * sc;
}

// ---------------- K2: fused normalize + depthwise 5x5x5 (pad 2) ----------------
#define K2D 12
#define K2H 12
#define K2W 36
__global__ __launch_bounds__(256) void k_conv5(const float* __restrict__ x,
                                               const float* __restrict__ w0,
                                               const float* __restrict__ b0,
                                               const float* __restrict__ wsf,
                                               float* __restrict__ attn0) {
    __shared__ float sh[K2D * K2H * K2W];
    __shared__ float wt[125];
    int tid = threadIdx.x;
    int tx = tid & 31;
    int ty = tid >> 5;
    int wtile = blockIdx.x;        // 0..1
    int dt = blockIdx.y & 7;       // 0..7
    int ht = blockIdx.y >> 3;      // 0..7
    int nc = blockIdx.z;           // 0..127
    int c = nc & 63;
    int w0i = wtile * 32;
    int h0 = ht * 8;
    int d0 = dt * 8;
    const float* xb = x + (size_t)nc * SPATIAL;
    float sc = wsf[128 + c], shv = wsf[192 + c];
    if (tid < 125) wt[tid] = w0[c * 125 + tid];
    for (int idx = tid; idx < K2D * K2H * K2W; idx += 256) {
        int z = idx / (K2H * K2W);
        int rem = idx - z * (K2H * K2W);
        int y = rem / K2W;
        int xw = rem - y * K2W;
        int gd = d0 - 2 + z, gh = h0 - 2 + y, gw = w0i - 2 + xw;
        float v = 0.f;
        if ((unsigned)gd < 64u && (unsigned)gh < 64u && (unsigned)gw < 64u)
            v = xb[(size_t)gd * PLANE_SZ + gh * 64 + gw] * sc + shv;
        sh[idx] = v;
    }
    __syncthreads();
    float acc[8] = {0,0,0,0,0,0,0,0};
    #pragma unroll
    for (int z = 0; z < 12; ++z) {
        #pragma unroll
        for (int j = 0; j < 5; ++j) {
            #pragma unroll
            for (int k = 0; k < 5; ++k) {
                float v = sh[(z * K2H + (ty + j)) * K2W + tx + k];
                #pragma unroll
                for (int i = 0; i < 5; ++i) {
                    int dz = z - i;
                    if (dz >= 0 && dz < 8)
                        acc[dz] += wt[(i * 5 + j) * 5 + k] * v;
                }
            }
        }
    }
    float bias = b0[c];
    float* ob = attn0 + (size_t)nc * SPATIAL + (size_t)(h0 + ty) * 64 + w0i + tx;
    #pragma unroll
    for (int dz = 0; dz < 8; ++dz)
        ob[(size_t)(d0 + dz) * PLANE_SZ] = acc[dz] + bias;
}

// ---------------- K3 v3: dilated depthwise 7x7x7, dil=3, pad 9 ----------------
// Residue decomposition in d (thread computes 8 outputs d = 3*(j0+q)+rd), with
// the 14 plane-stages emitted as STRAIGHT-LINE templated code so q = P - t is
// a compile-time constant -> acc[] statically indexed -> stays in VGPRs.
// (R2 failure: outer p-loop didn't unroll, acc[q] went dynamic -> scratch,
//  VGPR_Count=16 and 14x VALU bloat.)
#define ROWS7 22
#define COLS7 84   /* 82 valid + 2 pad */

template<int P>
__device__ __forceinline__ void conv7_stage(const float* __restrict__ ab,
                                            const float* __restrict__ wc,
                                            float* __restrict__ sh,
                                            int tid, int hh, int w, int h0,
                                            int j0, int rd, float (&acc)[8]) {
    int m = j0 - 3 + P;
    int z = 3 * m + rd;
    bool zok = (m >= 0) && (z < 64);   // block-uniform
    __syncthreads();                   // protect LDS from previous stage's readers
    if (zok) {
        const float* pb = ab + (size_t)z * PLANE_SZ;
        #pragma unroll
        for (int k = 0; k < 8; ++k) {
            int idx = k * 256 + tid;
            if (idx < ROWS7 * COLS7) {
                int row = idx / COLS7;
                int col = idx - row * COLS7;
                int gy = h0 - 9 + row;
                int gx = col - 9;
                float v = 0.f;
                if (col < 82 && (unsigned)gy < 64u && (unsigned)gx < 64u)
                    v = pb[gy * 64 + gx];
                sh[idx] = v;
            }
        }
    }
    __syncthreads();
    if (zok) {
        #pragma unroll
        for (int v = 0; v < 7; ++v) {
            float val[7];
            int rb = (hh + 3 * v) * COLS7 + w;
            #pragma unroll
            for (int u = 0; u < 7; ++u) val[u] = sh[rb + 3 * u];
            #pragma unroll
            for (int t = 0; t < 7; ++t) {
                const int q = P - t;               // compile-time
                if (q >= 0 && q < 8) {
                    #pragma unroll
                    for (int u = 0; u < 7; ++u)
                        acc[q] = fmaf(wc[t * 49 + v * 7 + u], val[u], acc[q]);
                }
            }
        }
    }
}

__global__ __launch_bounds__(256) void k_conv7(const float* __restrict__ attn0,
                                               const float* __restrict__ wsv,
                                               const float* __restrict__ bs,
                                               float* __restrict__ attn1) {
    __shared__ float sh[ROWS7 * COLS7];
    int tid = threadIdx.x;
    int w = tid & 63;
    int hh = tid >> 6;             // 0..3
    int ht = blockIdx.x;           // 0..15
    int rd = blockIdx.y % 3;       // residue class in d
    int j0 = (blockIdx.y / 3) * 8; // 0,8,16
    int nc = blockIdx.z;
    int c = nc & 63;
    int h0 = ht * 4;
    int h = h0 + hh;
    const float* ab = attn0 + (size_t)nc * SPATIAL;
    const float* wc = wsv + c * 343;   // block-uniform -> scalar loads
    float acc[8] = {0,0,0,0,0,0,0,0};

    conv7_stage< 0>(ab, wc, sh, tid, hh, w, h0, j0, rd, acc);
    conv7_stage< 1>(ab, wc, sh, tid, hh, w, h0, j0, rd, acc);
    conv7_stage< 2>(ab, wc, sh, tid, hh, w, h0, j0, rd, acc);
    conv7_stage< 3>(ab, wc, sh, tid, hh, w, h0, j0, rd, acc);
    conv7_stage< 4>(ab, wc, sh, tid, hh, w, h0, j0, rd, acc);
    conv7_stage< 5>(ab, wc, sh, tid, hh, w, h0, j0, rd, acc);
    conv7_stage< 6>(ab, wc, sh, tid, hh, w, h0, j0, rd, acc);
    conv7_stage< 7>(ab, wc, sh, tid, hh, w, h0, j0, rd, acc);
    conv7_stage< 8>(ab, wc, sh, tid, hh, w, h0, j0, rd, acc);
    conv7_stage< 9>(ab, wc, sh, tid, hh, w, h0, j0, rd, acc);
    conv7_stage<10>(ab, wc, sh, tid, hh, w, h0, j0, rd, acc);
    conv7_stage<11>(ab, wc, sh, tid, hh, w, h0, j0, rd, acc);
    conv7_stage<12>(ab, wc, sh, tid, hh, w, h0, j0, rd, acc);
    conv7_stage<13>(ab, wc, sh, tid, hh, w, h0, j0, rd, acc);

    float bias = bs[c];
    float* ob = attn1 + (size_t)nc * SPATIAL + (size_t)h * 64 + w;
    #pragma unroll
    for (int q = 0; q < 8; ++q) {
        int d = 3 * (j0 + q) + rd;
        if (d < 64)
            ob[(size_t)d * PLANE_SZ] = acc[q] + bias;
    }
}

// ---------------- K4: pointwise 1x1x1 (64->64) + bias + gate by x ----------------
__global__ __launch_bounds__(256) void k_pointwise(const float* __restrict__ attn1,
                                                   const float* __restrict__ x,
                                                   const float* __restrict__ w1,
                                                   const float* __restrict__ b1,
                                                   float* __restrict__ out) {
    __shared__ float at[64 * 64];
    int tid = threadIdx.x;
    int sl = tid & 63;
    int cg = __builtin_amdgcn_readfirstlane(tid >> 6);  // 0..3, wave-uniform
    int s0 = blockIdx.x * 64;
    int n = blockIdx.y;
    const float* a_base = attn1 + (size_t)n * C_DIM * SPATIAL + s0;
    #pragma unroll
    for (int it = 0; it < 16; ++it) {
        int idx = it * 256 + tid;
        int row = idx >> 6;
        at[idx] = a_base[(size_t)row * SPATIAL + sl];
    }
    __syncthreads();
    float acc[16];
    #pragma unroll
    for (int j = 0; j < 16; ++j) acc[j] = 0.f;
    for (int ci = 0; ci < 64; ++ci) {
        float va = at[ci * 64 + sl];
        #pragma unroll
        for (int j = 0; j < 16; ++j) {
            int cc = cg * 16 + j;
            acc[j] += w1[cc * 64 + ci] * va;   // wave-uniform -> scalar loads
        }
    }
    const float* xb = x + (size_t)n * C_DIM * SPATIAL + s0;
    float* ob = out + (size_t)n * C_DIM * SPATIAL + s0;
    #pragma unroll
    for (int j = 0; j < 16; ++j) {
        int cc = cg * 16 + j;
        float attn = acc[j] + b1[cc];
        ob[(size_t)cc * SPATIAL + sl] = xb[(size_t)cc * SPATIAL + sl] * attn;
    }
}

extern "C" void kernel_launch(void* const* d_in, const int* in_sizes, int n_in,
                              void* d_out, int out_size, void* d_ws, size_t ws_size,
                              hipStream_t stream) {
    const float* x     = (const float*)d_in[0];
    const float* gamma = (const float*)d_in[1];
    const float* beta  = (const float*)d_in[2];
    const float* w0    = (const float*)d_in[3];
    const float* b0    = (const float*)d_in[4];
    const float* wsv   = (const float*)d_in[5];
    const float* bs    = (const float*)d_in[6];
    const float* w1    = (const float*)d_in[7];
    const float* b1    = (const float*)d_in[8];
    float* out = (float*)d_out;
    float* wsf = (float*)d_ws;
    float* attn1 = wsf + 256;   // 134 MB intermediate in workspace

    hipMemsetAsync(d_ws, 0, 1024, stream);
    k_stats<<<dim3(1024), dim3(256), 0, stream>>>(x, wsf);
    k_finalize<<<dim3(1), dim3(64), 0, stream>>>(wsf, gamma, beta);
    // attn0 lives in d_out; overwritten later by K4 (stream-ordered, safe)
    k_conv5<<<dim3(2, 64, 128), dim3(256), 0, stream>>>(x, w0, b0, wsf, out);
    k_conv7<<<dim3(16, 9, 128), dim3(256), 0, stream>>>(out, wsv, bs, attn1);
    k_pointwise<<<dim3(4096, 2), dim3(256), 0, stream>>>(attn1, x, w1, b1, out);
}